// Round 10
// baseline (1892.755 us; speedup 1.0000x reference)
//
#include <hip/hip_runtime.h>

#define NSAMP 32768
#define INB   4
#define HIDN  4
#define CHN   2
#define OUTD  10
#define NPIX  196
#define NPAIR 97             /* 194 middle BN steps, processed 2 per grid sync */
#define BLK   512
#define NBLK  (NSAMP / BLK)  /* 64 blocks, 1 sample per thread */
#define NCOMP 192            /* 184 moment comps + 8 pad */
#define INV_ROWS 1.52587890625e-05f   /* 1/(N*CH) = 1/65536 */
#define BN_EPS 1e-5f
#define SENTW 0xFFFFFFFFu    /* negative-NaN sentinel, unreachable by finite math */
/* ws: pay[NPAIR][NBLK][NCOMP] f32, relaxed agent u32 stores; merged sentinel-
   gather (per-word check -> word atomicity suffices). No atomics, deterministic. */
#define WS_BYTES ((size_t)NPAIR * NBLK * NCOMP * 4)

/* Moment layout (totals, also LDS 'tot'):
   0-3 S1[h] | 4-7 S2[h] | 8-23 A[h][hp]=Σ u_h Mp_h,hp | 24-39 B[h][hp]=Σ Mp_h,hp
   40-79 C[p][hp]=Σ u_h u_g Mp_h Mp_g (sym pairs) | 80-143 D[h][g][hp]=Σ u_h Mp_h Mp_g
   144-183 E[p][hp]=Σ Mp_h Mp_g | 184-191 pad */

__device__ __forceinline__ float comp_val(const int k, const float u[CHN][4],
                                          const float Mp[CHN][4][4]) {
    constexpr int ph[10] = {0,0,0,0,1,1,1,2,2,3};
    constexpr int pg[10] = {0,1,2,3,1,2,3,2,3,3};
    float s = 0.f;
    if (k < 4) {
#pragma unroll
        for (int c = 0; c < CHN; ++c) s += u[c][k];
    } else if (k < 8) {
        const int h = k - 4;
#pragma unroll
        for (int c = 0; c < CHN; ++c) s = fmaf(u[c][h], u[c][h], s);
    } else if (k < 24) {
        const int h = (k - 8) >> 2, hp = k & 3;
#pragma unroll
        for (int c = 0; c < CHN; ++c) s = fmaf(u[c][h], Mp[c][h][hp], s);
    } else if (k < 40) {
        const int h = (k - 24) >> 2, hp = k & 3;
#pragma unroll
        for (int c = 0; c < CHN; ++c) s += Mp[c][h][hp];
    } else if (k < 80) {
        const int p = (k - 40) >> 2, hp = k & 3, h = ph[p], g = pg[p];
#pragma unroll
        for (int c = 0; c < CHN; ++c)
            s = fmaf(u[c][h] * u[c][g], Mp[c][h][hp] * Mp[c][g][hp], s);
    } else if (k < 144) {
        const int idx = k - 80, h = idx >> 4, g = (idx >> 2) & 3, hp = k & 3;
#pragma unroll
        for (int c = 0; c < CHN; ++c)
            s = fmaf(u[c][h], Mp[c][h][hp] * Mp[c][g][hp], s);
    } else if (k < 184) {
        const int p = (k - 144) >> 2, hp = k & 3, h = ph[p], g = pg[p];
#pragma unroll
        for (int c = 0; c < CHN; ++c) s = fmaf(Mp[c][h][hp], Mp[c][g][hp], s);
    }
    return s;
}

/* Reduce over 64 lanes of 32 per-lane partials; lane ln ends holding the
   wave-total of comp (ln&31). Peak live set: 32 regs. */
__device__ __forceinline__ float scatter32(float v[32], int ln) {
#pragma unroll
    for (int j = 0; j < 32; ++j) v[j] += __shfl_xor(v[j], 32);
#pragma unroll
    for (int b = 0; b < 5; ++b) {
        const int d = 1 << b;
        const bool hi = (ln >> b) & 1;
#pragma unroll
        for (int j = 0; j < (32 >> (b + 1)); ++j) {
            float keep = hi ? v[2 * j + 1] : v[2 * j];
            float send = hi ? v[2 * j]     : v[2 * j + 1];
            v[j] = keep + __shfl_xor(send, d);
        }
    }
    return v[0];
}

__global__ __launch_bounds__(BLK, 1)   /* min 1 wave/EU -> 256-VGPR budget, no spill */
void ttbn_main(const float* __restrict__ x,  const float* __restrict__ wf,
               const float* __restrict__ wm, const float* __restrict__ wl,
               const float* __restrict__ gamma, const float* __restrict__ beta,
               float* __restrict__ out, float* __restrict__ ws)
{
    __shared__ float wb[8][6][32];     // per-wave scatter results
    __shared__ float sum2[2][NCOMP];   // gather halves
    __shared__ float tot[NCOMP];       // grid totals
    const int tid = threadIdx.x;
    const int ln  = tid & 63, wv = tid >> 6;
    const long n  = (long)blockIdx.x * BLK + tid;

    float gm[HIDN], bt[HIDN];
#pragma unroll
    for (int h = 0; h < HIDN; ++h) { gm[h] = gamma[h]; bt[h] = beta[h]; }

    const float* xrow = x + n * (INB * NPIX);

    // ---- pixel 0 (no BN) ----
    float y[CHN][HIDN];
    {
        float x0[INB];
#pragma unroll
        for (int i = 0; i < INB; ++i) x0[i] = xrow[i * NPIX];
#pragma unroll
        for (int c = 0; c < CHN; ++c)
#pragma unroll
            for (int h = 0; h < HIDN; ++h) {
                float acc = 0.f;
#pragma unroll
                for (int i = 0; i < INB; ++i)
                    acc = fmaf(x0[i], wf[(i * HIDN + h) * CHN + c], acc);
                y[c][h] = acc;
            }
    }
    float xa[INB], xb[INB];   // pair-0 pixels (1,2)
#pragma unroll
    for (int i = 0; i < INB; ++i) { xa[i] = xrow[i * NPIX + 1]; xb[i] = xrow[i * NPIX + 2]; }

#pragma unroll 1
    for (int j = 0; j < NPAIR; ++j) {
        const float* w0 = wm + (size_t)(2 * j) * 128;
        const float* w1 = w0 + 128;

        // u = y · M(xa,w0), M streamed (never materialized)
        float u[CHN][HIDN] = {{0.f,0.f,0.f,0.f},{0.f,0.f,0.f,0.f}};
#pragma unroll
        for (int r = 0; r < 4; ++r)
#pragma unroll
            for (int h = 0; h < 4; ++h)
#pragma unroll
                for (int c = 0; c < CHN; ++c) {
                    float m = 0.f;
#pragma unroll
                    for (int i = 0; i < INB; ++i)
                        m = fmaf(xa[i], w0[(r * 16 + i * 4 + h) * 2 + c], m);
                    u[c][h] = fmaf(y[c][r], m, u[c][h]);
                }
        // Mp(xb,w1)
        float Mp[CHN][4][4];
#pragma unroll
        for (int r = 0; r < 4; ++r)
#pragma unroll
            for (int h = 0; h < 4; ++h)
#pragma unroll
                for (int c = 0; c < CHN; ++c) {
                    float m = 0.f;
#pragma unroll
                    for (int i = 0; i < INB; ++i)
                        m = fmaf(xb[i], w1[(r * 16 + i * 4 + h) * 2 + c], m);
                    Mp[c][r][h] = m;
                }
        // prefetch next pair's pixels (hides HBM latency under moments+sync)
        float xa2[INB], xb2[INB];
        if (j < NPAIR - 1) {
#pragma unroll
            for (int i = 0; i < INB; ++i) {
                xa2[i] = xrow[i * NPIX + 2 * j + 3];
                xb2[i] = xrow[i * NPIX + 2 * j + 4];
            }
        }
        // ---- 6 banks of 32 comps: compute + reduce-scatter, LDS write inside
        //      the loop so only ONE v[32] is live at a time ----
#pragma unroll
        for (int b = 0; b < 6; ++b) {
            float v[32];
#pragma unroll
            for (int q = 0; q < 32; ++q) v[q] = comp_val(b * 32 + q, u, Mp);
            float r = scatter32(v, ln);
            if (ln < 32) wb[wv][b][ln] = r;
        }
        __syncthreads();
        // cross-wave combine + payload store (192 threads)
        if (tid < NCOMP) {
            float s = 0.f;
#pragma unroll
            for (int w = 0; w < 8; ++w) s += wb[w][tid >> 5][tid & 31];
            __hip_atomic_store((unsigned*)ws + ((size_t)j * NBLK + blockIdx.x) * NCOMP + tid,
                               __float_as_uint(s), __ATOMIC_RELAXED, __HIP_MEMORY_SCOPE_AGENT);
        }
        // merged sentinel-gather: thread (half,k) sums comp k over 32 blocks
        if (tid < 2 * NCOMP) {
            const int half = tid >= NCOMP ? 1 : 0;
            const int k = tid - half * NCOMP;
            const unsigned* gp = (const unsigned*)ws + ((size_t)j * NBLK + half * 32) * NCOMP + k;
            float s; bool ok;
            do {
                ok = true; s = 0.f;
#pragma unroll
                for (int b = 0; b < 32; ++b) {
                    unsigned wd = __hip_atomic_load(gp + (size_t)b * NCOMP, __ATOMIC_RELAXED,
                                                    __HIP_MEMORY_SCOPE_AGENT);
                    ok = ok && (wd != SENTW);
                    s += __uint_as_float(wd);
                }
            } while (__any(!ok));
            sum2[half][k] = s;
        }
        __syncthreads();
        if (tid < NCOMP) tot[tid] = sum2[0][tid] + sum2[1][tid];
        __syncthreads();

        // ---- recombine BN coefs for both steps (redundant per thread) ----
        constexpr int ph[10] = {0,0,0,0,1,1,1,2,2,3};
        constexpr int pg[10] = {0,1,2,3,1,2,3,2,3,3};
        float is_[4], sh_[4];
#pragma unroll
        for (int h = 0; h < 4; ++h) {
            float m  = tot[h] * INV_ROWS;
            float va = fmaf(-m, m, tot[4 + h] * INV_ROWS);
            float r  = rsqrtf(va + BN_EPS) * gm[h];
            is_[h] = r; sh_[h] = bt[h] - m * r;
        }
        float is2[4], sh2[4];
#pragma unroll
        for (int hp = 0; hp < 4; ++hp) {
            float s1 = 0.f;
#pragma unroll
            for (int h = 0; h < 4; ++h) {
                s1 = fmaf(is_[h], tot[8  + h * 4 + hp], s1);
                s1 = fmaf(sh_[h], tot[24 + h * 4 + hp], s1);
            }
            float s2 = 0.f;
#pragma unroll
            for (int p = 0; p < 10; ++p) {
                const int h = ph[p], g = pg[p];
                const float f = (h == g) ? 1.f : 2.f;
                s2 = fmaf(f * is_[h] * is_[g], tot[40  + p * 4 + hp], s2);
                s2 = fmaf(f * sh_[h] * sh_[g], tot[144 + p * 4 + hp], s2);
            }
#pragma unroll
            for (int h = 0; h < 4; ++h)
#pragma unroll
                for (int g = 0; g < 4; ++g)
                    s2 = fmaf(2.f * is_[h] * sh_[g], tot[80 + (h * 4 + g) * 4 + hp], s2);
            float m2  = s1 * INV_ROWS;
            float va2 = fmaf(-m2, m2, s2 * INV_ROWS);
            float r2  = rsqrtf(va2 + BN_EPS) * gm[hp];
            is2[hp] = r2; sh2[hp] = bt[hp] - m2 * r2;
        }
        // ---- advance state through both steps ----
#pragma unroll
        for (int c = 0; c < CHN; ++c) {
            float yp[4];
#pragma unroll
            for (int h = 0; h < 4; ++h) yp[h] = fmaf(u[c][h], is_[h], sh_[h]);
#pragma unroll
            for (int hp = 0; hp < 4; ++hp) {
                float up = 0.f;
#pragma unroll
                for (int h = 0; h < 4; ++h) up = fmaf(yp[h], Mp[c][h][hp], up);
                y[c][hp] = fmaf(up, is2[hp], sh2[hp]);
            }
        }
        if (j < NPAIR - 1) {
#pragma unroll
            for (int i = 0; i < INB; ++i) { xa[i] = xa2[i]; xb[i] = xb2[i]; }
        }
    }

    // ---- final step: pixel 195 with wl, no BN ----
    {
        float xv[INB];
#pragma unroll
        for (int i = 0; i < INB; ++i) xv[i] = xrow[i * NPIX + 195];
        float o0[OUTD], o1[OUTD];
#pragma unroll
        for (int od = 0; od < OUTD; ++od) { o0[od] = 0.f; o1[od] = 0.f; }
#pragma unroll
        for (int r = 0; r < 4; ++r)
#pragma unroll
            for (int i = 0; i < INB; ++i) {
                float p0 = y[0][r] * xv[i];
                float p1 = y[1][r] * xv[i];
                const float* wri = wl + r * (INB * OUTD * CHN) + i * (OUTD * CHN);
#pragma unroll
                for (int od = 0; od < OUTD; ++od) {
                    o0[od] = fmaf(p0, wri[od * CHN + 0], o0[od]);
                    o1[od] = fmaf(p1, wri[od * CHN + 1], o1[od]);
                }
            }
        float tmp[20];
#pragma unroll
        for (int od = 0; od < OUTD; ++od) { tmp[od] = o0[od]; tmp[10 + od] = o1[od]; }
        float4* o4 = reinterpret_cast<float4*>(out + n * (CHN * OUTD));
#pragma unroll
        for (int q = 0; q < 5; ++q)
            o4[q] = make_float4(tmp[q * 4], tmp[q * 4 + 1], tmp[q * 4 + 2], tmp[q * 4 + 3]);
    }
}

extern "C" void kernel_launch(void* const* d_in, const int* in_sizes, int n_in,
                              void* d_out, int out_size, void* d_ws, size_t ws_size,
                              hipStream_t stream) {
    const float* x     = (const float*)d_in[0];
    const float* wf    = (const float*)d_in[1];
    const float* wm    = (const float*)d_in[2];
    const float* wl    = (const float*)d_in[3];
    const float* gamma = (const float*)d_in[4];
    const float* beta  = (const float*)d_in[5];
    float*       out   = (float*)d_out;
    float*       ws    = (float*)d_ws;

    // sentinel-fill payload area (0xFF bytes == SENTW in every word)
    hipMemsetAsync(d_ws, 0xFF, WS_BYTES, stream);

    void* args[] = { &x, &wf, &wm, &wl, &gamma, &beta, &out, &ws };
    hipLaunchCooperativeKernel((void*)ttbn_main, dim3(NBLK), dim3(BLK),
                               args, 0, stream);
}